// Round 4
// baseline (3564.265 us; speedup 1.0000x reference)
//
#include <hip/hip_runtime.h>

#define B_ 512
#define S_ 256
#define V_ 128
#define E_ 64
#define H_ 128
#define NT_ 512
#define PAD_ 129
#define SMEM_BYTES ((S_*PAD_ + 2*H_ + H_ + H_ + S_ + H_ + 8) * 4)

// load float from possibly-bf16 array (flag: 1=f32, 0=bf16)
__device__ __forceinline__ float ldf(const void* p, long i, int isf){
  if (isf) return ((const float*)p)[i];
  unsigned v = ((const unsigned short*)p)[i];
  union{unsigned u; float f;} c; c.u = v << 16; return c.f;
}

// ---------------- dtype sniff: first 512 bytes of one_hot_inputs ----------------
// f32: 512B = row 0 (128 elems, exactly one 1.0f) -> exactly 1 nonzero uint16
// bf16: 512B = rows 0+1 (256 elems, one 1.0 each) -> exactly 2 nonzero uint16
__global__ void k_sniff(const unsigned short* oh, int* flag){
  if (threadIdx.x == 0){
    int cnt = 0;
    for (int i = 0; i < 256; ++i) cnt += (oh[i] != 0);
    *flag = (cnt == 1) ? 1 : 0;
  }
}

// ---------------- generic convert-to-f32 (copy when already f32) ----------------
__global__ void k_cvt(const void* src, float* dst, int n, const int* flag){
  int i = blockIdx.x*blockDim.x + threadIdx.x;
  if (i < n) dst[i] = ldf(src, i, *flag);
}

// ---------------- lens: mask dtype sniffed (u8 / i32 / bf16 / f32) ----------------
// first two elements are guaranteed true (len >= 64):
//   u8  : 01 01 ...            i32 : 01 00 00 00 ...
//   bf16: 80 3F 80 3F ...      f32 : 00 00 80 3F ...
__global__ void k_lens(const void* maskp, int* lens){
  int b = blockIdx.x*blockDim.x + threadIdx.x;
  if (b >= B_) return;
  const unsigned char* mc = (const unsigned char*)maskp;
  int mode;
  if (mc[0] == 1 && mc[1] == 1) mode = 0;
  else if (mc[0] == 1)          mode = 1;
  else if (mc[0] == 0x80)       mode = 2;
  else                          mode = 3;
  int cnt = 0;
  for (int j = 0; j < S_; ++j){
    long idx = (long)b*S_ + j; int v;
    if (mode == 0)      v = (mc[idx] != 0);
    else if (mode == 1) v = (((const int*)maskp)[idx] != 0);
    else if (mode == 2) v = (((const unsigned short*)maskp)[idx] != 0);
    else                v = (((const float*)maskp)[idx] > 0.5f);
    cnt += v;
  }
  lens[b] = cnt;
}

// ---------------- one-hot -> token index (dtype-adaptive) ----------------
__global__ void k_ids(const void* ohin, const void* ohout, const int* flag,
                      int* __restrict__ idsIn, int* __restrict__ idsOut){
  int row = blockIdx.x*blockDim.x + threadIdx.x;
  if (row >= B_*S_) return;
  long base = (long)row * V_;
  int isf = *flag;
  int ia = 0, ib = 0;
  if (isf){
    const float* a = (const float*)ohin; const float* c = (const float*)ohout;
    for (int v = 0; v < V_; ++v){
      if (a[base+v] > 0.5f) ia = v;
      if (c[base+v] > 0.5f) ib = v;
    }
  } else {
    const unsigned short* a = (const unsigned short*)ohin;
    const unsigned short* c = (const unsigned short*)ohout;
    for (int v = 0; v < V_; ++v){
      if (a[base+v] >= 0x3F00u) ia = v;   // bf16(1.0)=0x3F80, bf16(0)=0
      if (c[base+v] >= 0x3F00u) ib = v;
    }
  }
  idsIn[row] = ia; idsOut[row] = ib;
}

// ---------------- fold embedding + input projection + biases into [V][H] tables ----------------
__global__ void k_tables(const void* W_emb, const void* b_emb,
                         const void* W_ih_e, const void* b_ih_e, const void* b_hh_e,
                         const void* W_ih_d, const void* b_ih_d, const void* b_hh_d,
                         const int* flag,
                         float* __restrict__ encT, float* __restrict__ decT,
                         float* __restrict__ posT){
  int v = blockIdx.x, h = threadIdx.x;
  int isf = *flag;
  float ae = 0.f, ad = 0.f;
  for (int e = 0; e < E_; ++e){
    float x = ldf(W_emb, (long)e*V_ + v, isf) + ldf(b_emb, e, isf);
    ae = fmaf(ldf(W_ih_e, (long)h*(E_+V_) + e, isf), x, ae);
    ad = fmaf(ldf(W_ih_d, (long)h*E_ + e, isf), x, ad);
  }
  encT[v*H_ + h] = ae + ldf(b_ih_e, h, isf) + ldf(b_hh_e, h, isf);
  decT[v*H_ + h] = ad + ldf(b_ih_d, h, isf) + ldf(b_hh_d, h, isf);
  posT[v*H_ + h] = ldf(W_ih_e, (long)h*(E_+V_) + E_ + v, isf);  // positional one-hot column (st<128)
}

// ---------------- main: one workgroup (512 thr) per batch row, pure f32 ----------------
__global__ __launch_bounds__(NT_, 1) void k_main(
    const int* __restrict__ idsIn, const int* __restrict__ idsOut, const int* __restrict__ lens,
    const float* __restrict__ encT, const float* __restrict__ decT, const float* __restrict__ posT,
    const float* __restrict__ W_hh_e, const float* __restrict__ W_e2d, const float* __restrict__ b_e2d,
    const float* __restrict__ W_hh_d, const float* __restrict__ W_out, const float* __restrict__ b_out,
    float* __restrict__ out)
{
  extern __shared__ __align__(16) char smem[];
  float* encS   = (float*)smem;            // [S_][PAD_]  padded, conflict-free both axes
  float* hv0    = encS + S_*PAD_;
  float* hv1    = hv0 + H_;
  float* nxt    = hv1 + H_;
  float* dec    = nxt + H_;
  float* scr    = dec + H_;                // [S_]
  float* logits = scr + S_;
  float* red    = logits + H_;

  const int b = blockIdx.x, t = threadIdx.x;
  const int h = t >> 2, q4 = t & 3;        // matvec: 4 threads per output row
  const int len = lens[b];

  // out row 0: log(full(EPS).at[:,0].set(1))
  if (t < V_) out[(size_t)b*S_*V_ + t] = (t==0) ? 0.f : -46.051701859880914f;

  float4 wrq[8];
  { const float4* W4 = (const float4*)W_hh_e;
    #pragma unroll
    for (int r=0;r<8;++r) wrq[r] = W4[h*32 + q4*8 + r]; }

  if (t < H_){ hv0[t]=0.f; hv1[t]=0.f; }
  __syncthreads();

  // -------- encoder --------
  const int* idsInB = idsIn + b*S_;
  int cur = 0;
  for (int st=0; st<S_; ++st){
    if (st < len){   // len uniform across block -> barrier inside is legal
      const float* hvc = cur ? hv1 : hv0;
      const float4* hp = (const float4*)(hvc + q4*32);
      float acc = 0.f;
      #pragma unroll
      for (int r=0;r<8;++r){ float4 u = hp[r];
        acc = fmaf(wrq[r].x,u.x,acc); acc = fmaf(wrq[r].y,u.y,acc);
        acc = fmaf(wrq[r].z,u.z,acc); acc = fmaf(wrq[r].w,u.w,acc); }
      acc += __shfl_xor(acc,1); acc += __shfl_xor(acc,2);
      if (q4==0){
        float pre = acc + encT[idsInB[st]*H_ + h];
        if (st < V_) pre += posT[st*H_ + h];
        (cur ? hv0 : hv1)[h] = tanhf(pre);
      }
      __syncthreads();
      cur ^= 1;
    }
    { const float* hvc = cur ? hv1 : hv0;
      if (t < H_) encS[st*PAD_ + t] = hvc[t]; }
    __syncthreads();
  }

  // decoder weights
  float4 wdq[8], woq[8];
  { const float4* Wd4 = (const float4*)W_hh_d;
    const float4* Wo4 = (const float4*)W_out;
    #pragma unroll
    for (int r=0;r<8;++r){ wdq[r] = Wd4[h*32+q4*8+r]; woq[r] = Wo4[h*32+q4*8+r]; } }

  // -------- decode_init: nxt = enc_last @ W_e2d^T + b_e2d (pre-attention) --------
  { const float* hvc = cur ? hv1 : hv0;
    const float4* hp  = (const float4*)(hvc + q4*32);
    const float4* We4 = (const float4*)W_e2d;
    float acc = 0.f;
    #pragma unroll
    for (int r=0;r<8;++r){ float4 u = hp[r]; float4 w = We4[h*32+q4*8+r];
      acc = fmaf(w.x,u.x,acc); acc = fmaf(w.y,u.y,acc);
      acc = fmaf(w.z,u.z,acc); acc = fmaf(w.w,u.w,acc); }
    acc += __shfl_xor(acc,1); acc += __shfl_xor(acc,2);
    if (q4==0) nxt[h] = acc + b_e2d[h];
  }
  __syncthreads();

  // -------- decode loop, reference order:
  // carry = attend(nxt);  per j: nxt=tanh(decT[id_j]+Wd*carry); carry=attend(nxt);
  // out[j+1] = log_softmax(Wo*carry + b_out)
  const int* idsOutB = idsOut + b*S_;
  for (int j = -1; j < S_-1; ++j){
    if (j >= 0){
      // nxt = tanh(decT[idsOut[j]] + W_hh_d @ dec)
      const float4* dp = (const float4*)(dec + q4*32);
      float acc = 0.f;
      #pragma unroll
      for (int r=0;r<8;++r){ float4 u = dp[r];
        acc = fmaf(wdq[r].x,u.x,acc); acc = fmaf(wdq[r].y,u.y,acc);
        acc = fmaf(wdq[r].z,u.z,acc); acc = fmaf(wdq[r].w,u.w,acc); }
      acc += __shfl_xor(acc,1); acc += __shfl_xor(acc,2);
      if (q4==0) nxt[h] = tanhf(acc + decT[idsOutB[j]*H_ + h]);
      __syncthreads();
    }

    // ---- attend: dec = nxt + softmax(nxt . enc) . enc ----
    if (t < S_){
      float s = 0.f;
      const float* er = encS + t*PAD_;
      #pragma unroll 8
      for (int jj=0;jj<H_;++jj) s = fmaf(er[jj], nxt[jj], s);
      scr[t] = s;
    }
    __syncthreads();
    if (t < 64){
      float v0 = scr[t];                                   // len>=64 -> always valid
      float v1 = (t+64  < len)? scr[t+64]  : -1e30f;
      float v2 = (t+128 < len)? scr[t+128] : -1e30f;
      float v3 = (t+192 < len)? scr[t+192] : -1e30f;
      float m = fmaxf(fmaxf(v0,v1), fmaxf(v2,v3));
      #pragma unroll
      for (int o=1;o<64;o<<=1) m = fmaxf(m, __shfl_xor(m,o));
      float e0 = expf(v0-m);
      float e1 = (t+64  < len)? expf(v1-m) : 0.f;
      float e2 = (t+128 < len)? expf(v2-m) : 0.f;
      float e3 = (t+192 < len)? expf(v3-m) : 0.f;
      scr[t]=e0; scr[t+64]=e1; scr[t+128]=e2; scr[t+192]=e3;
      float ss = (e0+e1)+(e2+e3);
      #pragma unroll
      for (int o=1;o<64;o<<=1) ss += __shfl_xor(ss,o);
      if (t==0) red[0] = 1.f/ss;
    }
    __syncthreads();
    if (t < H_){
      float c = 0.f;
      #pragma unroll 8
      for (int s=0;s<S_;++s) c = fmaf(scr[s], encS[s*PAD_ + t], c);
      dec[t] = nxt[t] + c*red[0];
    }
    __syncthreads();

    if (j >= 0){
      // ---- logits = W_out @ dec + b_out (from the NEW carry) ----
      { const float4* dp = (const float4*)(dec + q4*32);
        float acc = 0.f;
        #pragma unroll
        for (int r=0;r<8;++r){ float4 u = dp[r];
          acc = fmaf(woq[r].x,u.x,acc); acc = fmaf(woq[r].y,u.y,acc);
          acc = fmaf(woq[r].z,u.z,acc); acc = fmaf(woq[r].w,u.w,acc); }
        acc += __shfl_xor(acc,1); acc += __shfl_xor(acc,2);
        if (q4==0) logits[h] = acc + b_out[h];
      }
      __syncthreads();
      // ---- log-softmax -> out row j+1 ----
      if (t < 64){
        float a0 = logits[t], a1 = logits[t+64];
        float m = fmaxf(a0,a1);
        #pragma unroll
        for (int o=1;o<64;o<<=1) m = fmaxf(m, __shfl_xor(m,o));
        float ss = expf(a0-m) + expf(a1-m);
        #pragma unroll
        for (int o=1;o<64;o<<=1) ss += __shfl_xor(ss,o);
        float lse = m + logf(ss);
        size_t base = ((size_t)b*S_ + (size_t)(j+1))*(size_t)V_;
        out[base + t]      = a0 - lse;
        out[base + t + 64] = a1 - lse;
      }
      __syncthreads();
    }
  }
}

extern "C" void kernel_launch(void* const* d_in, const int* in_sizes, int n_in,
                              void* d_out, int out_size, void* d_ws, size_t ws_size,
                              hipStream_t stream)
{
  const void* ohin   = d_in[0];
  const void* ohout  = d_in[1];
  const void* maskp  = d_in[2];
  const void* W_emb  = d_in[3];
  const void* b_emb  = d_in[4];
  const void* W_ih_e = d_in[5];
  const void* W_hh_e = d_in[6];
  const void* b_ih_e = d_in[7];
  const void* b_hh_e = d_in[8];
  const void* W_e2d  = d_in[9];
  const void* b_e2d  = d_in[10];
  const void* W_ih_d = d_in[11];
  const void* W_hh_d = d_in[12];
  const void* b_ih_d = d_in[13];
  const void* b_hh_d = d_in[14];
  const void* W_out  = d_in[15];
  const void* b_out  = d_in[16];
  float* out = (float*)d_out;

  char* ws = (char*)d_ws;
  int* idsIn   = (int*)ws;   ws += (size_t)B_*S_*sizeof(int);
  int* idsOut  = (int*)ws;   ws += (size_t)B_*S_*sizeof(int);
  int* lens    = (int*)ws;   ws += 2048;
  int* flag    = (int*)ws;   ws += 1024;
  float* encT  = (float*)ws; ws += (size_t)V_*H_*sizeof(float);
  float* decT  = (float*)ws; ws += (size_t)V_*H_*sizeof(float);
  float* posT  = (float*)ws; ws += (size_t)V_*H_*sizeof(float);
  float* WheF  = (float*)ws; ws += (size_t)H_*H_*sizeof(float);
  float* WddF  = (float*)ws; ws += (size_t)H_*H_*sizeof(float);
  float* WooF  = (float*)ws; ws += (size_t)H_*H_*sizeof(float);
  float* WedF  = (float*)ws; ws += (size_t)H_*H_*sizeof(float);
  float* be2dF = (float*)ws; ws += 512;
  float* boutF = (float*)ws; ws += 512;

  (void)hipFuncSetAttribute((const void*)k_main,
                            hipFuncAttributeMaxDynamicSharedMemorySize, SMEM_BYTES);

  k_sniff<<<1, 64, 0, stream>>>((const unsigned short*)ohin, flag);
  k_lens<<<2, 256, 0, stream>>>(maskp, lens);
  k_ids<<<(B_*S_)/256, 256, 0, stream>>>(ohin, ohout, flag, idsIn, idsOut);
  k_tables<<<V_, H_, 0, stream>>>(W_emb, b_emb, W_ih_e, b_ih_e, b_hh_e,
                                  W_ih_d, b_ih_d, b_hh_d, flag, encT, decT, posT);
  k_cvt<<<(H_*H_+255)/256, 256, 0, stream>>>(W_hh_e, WheF, H_*H_, flag);
  k_cvt<<<(H_*H_+255)/256, 256, 0, stream>>>(W_hh_d, WddF, H_*H_, flag);
  k_cvt<<<(H_*H_+255)/256, 256, 0, stream>>>(W_out,  WooF, H_*H_, flag);
  k_cvt<<<(H_*H_+255)/256, 256, 0, stream>>>(W_e2d,  WedF, H_*H_, flag);
  k_cvt<<<1, 128, 0, stream>>>(b_e2d, be2dF, H_, flag);
  k_cvt<<<1, 128, 0, stream>>>(b_out, boutF, H_, flag);

  k_main<<<B_, NT_, SMEM_BYTES, stream>>>(idsIn, idsOut, lens, encT, decT, posT,
                                          WheF, WedF, be2dF,
                                          WddF, WooF, boutF, out);
}

// Round 5
// 1742.479 us; speedup vs baseline: 2.0455x; 2.0455x over previous
//
#include <hip/hip_runtime.h>

#define B_ 512
#define S_ 256
#define V_ 128
#define E_ 64
#define H_ 128
#define NT_ 512
#define ROWF_ 132   // enc row stride in floats (16B-aligned, fills are one-time)
#define SMEM_BYTES ((S_*ROWF_ + 2*H_ + H_ + H_ + S_ + H_)*4 + 16*32*16 + 32)

// load float from possibly-bf16 array (flag: 1=f32, 0=bf16)
__device__ __forceinline__ float ldf(const void* p, long i, int isf){
  if (isf) return ((const float*)p)[i];
  unsigned v = ((const unsigned short*)p)[i];
  union{unsigned u; float f;} c; c.u = v << 16; return c.f;
}

// ---------------- dtype sniff: first 512 bytes of one_hot_inputs ----------------
__global__ void k_sniff(const unsigned short* oh, int* flag){
  if (threadIdx.x == 0){
    int cnt = 0;
    for (int i = 0; i < 256; ++i) cnt += (oh[i] != 0);
    *flag = (cnt == 1) ? 1 : 0;
  }
}

// ---------------- generic convert-to-f32 ----------------
__global__ void k_cvt(const void* src, float* dst, int n, const int* flag){
  int i = blockIdx.x*blockDim.x + threadIdx.x;
  if (i < n) dst[i] = ldf(src, i, *flag);
}

// ---------------- lens: mask dtype sniffed (u8 / i32 / bf16 / f32) ----------------
__global__ void k_lens(const void* maskp, int* lens){
  int b = blockIdx.x*blockDim.x + threadIdx.x;
  if (b >= B_) return;
  const unsigned char* mc = (const unsigned char*)maskp;
  int mode;
  if (mc[0] == 1 && mc[1] == 1) mode = 0;
  else if (mc[0] == 1)          mode = 1;
  else if (mc[0] == 0x80)       mode = 2;
  else                          mode = 3;
  int cnt = 0;
  for (int j = 0; j < S_; ++j){
    long idx = (long)b*S_ + j; int v;
    if (mode == 0)      v = (mc[idx] != 0);
    else if (mode == 1) v = (((const int*)maskp)[idx] != 0);
    else if (mode == 2) v = (((const unsigned short*)maskp)[idx] != 0);
    else                v = (((const float*)maskp)[idx] > 0.5f);
    cnt += v;
  }
  lens[b] = cnt;
}

// ---------------- one-hot -> token index (dtype-adaptive) ----------------
__global__ void k_ids(const void* ohin, const void* ohout, const int* flag,
                      int* __restrict__ idsIn, int* __restrict__ idsOut){
  int row = blockIdx.x*blockDim.x + threadIdx.x;
  if (row >= B_*S_) return;
  long base = (long)row * V_;
  int isf = *flag;
  int ia = 0, ib = 0;
  if (isf){
    const float* a = (const float*)ohin; const float* c = (const float*)ohout;
    for (int v = 0; v < V_; ++v){
      if (a[base+v] > 0.5f) ia = v;
      if (c[base+v] > 0.5f) ib = v;
    }
  } else {
    const unsigned short* a = (const unsigned short*)ohin;
    const unsigned short* c = (const unsigned short*)ohout;
    for (int v = 0; v < V_; ++v){
      if (a[base+v] >= 0x3F00u) ia = v;
      if (c[base+v] >= 0x3F00u) ib = v;
    }
  }
  idsIn[row] = ia; idsOut[row] = ib;
}

// ---------------- fold embedding + input projection + biases into [V][H] tables ----------------
__global__ void k_tables(const void* W_emb, const void* b_emb,
                         const void* W_ih_e, const void* b_ih_e, const void* b_hh_e,
                         const void* W_ih_d, const void* b_ih_d, const void* b_hh_d,
                         const int* flag,
                         float* __restrict__ encT, float* __restrict__ decT,
                         float* __restrict__ posT){
  int v = blockIdx.x, h = threadIdx.x;
  int isf = *flag;
  float ae = 0.f, ad = 0.f;
  for (int e = 0; e < E_; ++e){
    float x = ldf(W_emb, (long)e*V_ + v, isf) + ldf(b_emb, e, isf);
    ae = fmaf(ldf(W_ih_e, (long)h*(E_+V_) + e, isf), x, ae);
    ad = fmaf(ldf(W_ih_d, (long)h*E_ + e, isf), x, ad);
  }
  encT[v*H_ + h] = ae + ldf(b_ih_e, h, isf) + ldf(b_hh_e, h, isf);
  decT[v*H_ + h] = ad + ldf(b_ih_d, h, isf) + ldf(b_hh_d, h, isf);
  posT[v*H_ + h] = ldf(W_ih_e, (long)h*(E_+V_) + E_ + v, isf);
}

// ---------------- main: one workgroup (512 thr) per batch row, register-resident attention ----------------
__global__ __launch_bounds__(NT_, 2) void k_main(
    const int* __restrict__ idsIn, const int* __restrict__ idsOut, const int* __restrict__ lens,
    const float* __restrict__ encT, const float* __restrict__ decT, const float* __restrict__ posT,
    const float* __restrict__ W_hh_e, const float* __restrict__ W_e2d, const float* __restrict__ b_e2d,
    const float* __restrict__ W_hh_d, const float* __restrict__ W_out, const float* __restrict__ b_out,
    float* __restrict__ out)
{
  extern __shared__ __align__(16) char smem[];
  float*  encS   = (float*)smem;                  // [256][ROWF_] (fills only)
  float*  hv0    = encS + S_*ROWF_;
  float*  hv1    = hv0 + H_;
  float*  nxtF   = hv1 + H_;
  float*  decF   = nxtF + H_;
  float*  scr    = decF + H_;                     // [256]
  float*  logits = scr + S_;
  float4* ctxP4  = (float4*)(logits + H_);        // [16][32] float4
  float*  red    = (float*)(ctxP4 + 16*32);

  const int b = blockIdx.x, t = threadIdx.x;
  const int h = t >> 2, q4 = t & 3;      // matvec: 4 threads / output row
  const int sid = t >> 1, half = t & 1;  // scores: 2 threads / enc row
  const int hq = t & 31, g = t >> 5;     // ctx: 32 h-chunks x 16 s-groups
  const int wave = t >> 6;
  const int len = lens[b];

  // out row 0: log(full(EPS).at[:,0].set(1))
  if (t < V_) out[(size_t)b*S_*V_ + t] = (t==0) ? 0.f : -46.051701859880914f;

  // encoder recurrent weights, XOR-staggered to kill 4-way bank conflicts on hv reads
  float4 wrq[8];
  #pragma unroll
  for (int r=0;r<8;++r) wrq[r] = ((const float4*)W_hh_e)[h*32 + q4*8 + (r^q4)];

  if (t < H_){ hv0[t]=0.f; hv1[t]=0.f; }
  __syncthreads();

  // -------- encoder: 1 barrier/step (ping-pong write target disjoint from reads) --------
  const int* idsInB = idsIn + b*S_;
  int cur = 0;
  for (int st=0; st<len; ++st){
    const float* hvc = cur ? hv1 : hv0;
    float* hvn = cur ? hv0 : hv1;
    const float4* hp = (const float4*)(hvc + q4*32);
    float a0=0.f, a1=0.f;
    #pragma unroll
    for (int r=0;r<8;r+=2){
      float4 u = hp[r^q4], v = hp[(r+1)^q4];
      a0 = fmaf(wrq[r].x,u.x,a0);   a0 = fmaf(wrq[r].y,u.y,a0);
      a0 = fmaf(wrq[r].z,u.z,a0);   a0 = fmaf(wrq[r].w,u.w,a0);
      a1 = fmaf(wrq[r+1].x,v.x,a1); a1 = fmaf(wrq[r+1].y,v.y,a1);
      a1 = fmaf(wrq[r+1].z,v.z,a1); a1 = fmaf(wrq[r+1].w,v.w,a1);
    }
    float acc = a0 + a1;
    acc += __shfl_xor(acc,1); acc += __shfl_xor(acc,2);
    if (q4==0){
      float pre = acc + encT[idsInB[st]*H_ + h];
      if (st < V_) pre += posT[st*H_ + h];
      hvn[h] = tanhf(pre);
    }
    __syncthreads();
    if (t < H_) encS[st*ROWF_ + t] = hvn[t];
    cur ^= 1;
  }
  // frozen rows len..255 replicate the last state
  { const float* hvc = cur ? hv1 : hv0;
    float v = hvc[t & 127];
    for (int row = len + (t>>7); row < S_; row += 4)
      encS[row*ROWF_ + (t & 127)] = v;
  }
  __syncthreads();

  // -------- one-time register fills (static indices -> VGPRs) --------
  float4 eR4[16], cR4[16];
  { const float4* eRow = (const float4*)(encS + sid*ROWF_) + half*16;
    #pragma unroll
    for (int r=0;r<16;++r) eR4[r] = eRow[r];
    #pragma unroll
    for (int j=0;j<16;++j) cR4[j] = *((const float4*)(encS + (g+16*j)*ROWF_) + hq);
  }

  // decoder weights (staggered); wrq dead from here (regalloc reuse)
  float4 wdq[8], woq[8];
  #pragma unroll
  for (int r=0;r<8;++r){
    wdq[r] = ((const float4*)W_hh_d)[h*32 + q4*8 + (r^q4)];
    woq[r] = ((const float4*)W_out )[h*32 + q4*8 + (r^q4)];
  }

  const int* idsOutB = idsOut + b*S_;

  // -------- decode loop: k=0 builds dec_0; iteration k>=1 builds dec_k.
  // logits lag one step: P1 of iter k computes Wo.dec_{k-1} -> out row k-1 (k>=2); row 255 in epilogue.
  for (int k=0; k<S_; ++k){
    // ---- P1: merged matvec ----
    if (k == 0){
      const float* hvc = cur ? hv1 : hv0;
      const float4* hp  = (const float4*)(hvc + q4*32);
      const float4* We4 = (const float4*)W_e2d + h*32 + q4*8;
      float a0=0.f;
      #pragma unroll
      for (int r=0;r<8;++r){ float4 u = hp[r]; float4 w = We4[r];
        a0 = fmaf(w.x,u.x,a0); a0 = fmaf(w.y,u.y,a0);
        a0 = fmaf(w.z,u.z,a0); a0 = fmaf(w.w,u.w,a0); }
      a0 += __shfl_xor(a0,1); a0 += __shfl_xor(a0,2);
      if (q4==0) nxtF[h] = a0 + b_e2d[h];
    } else {
      int id = idsOutB[k-1];
      const float4* dp = (const float4*)(decF + q4*32);
      float d0=0.f,d1=0.f,o0=0.f,o1=0.f;
      #pragma unroll
      for (int r=0;r<8;r+=2){
        float4 u = dp[r^q4], v = dp[(r+1)^q4];
        d0 = fmaf(wdq[r].x,u.x,d0);   d0 = fmaf(wdq[r].y,u.y,d0);
        d0 = fmaf(wdq[r].z,u.z,d0);   d0 = fmaf(wdq[r].w,u.w,d0);
        o0 = fmaf(woq[r].x,u.x,o0);   o0 = fmaf(woq[r].y,u.y,o0);
        o0 = fmaf(woq[r].z,u.z,o0);   o0 = fmaf(woq[r].w,u.w,o0);
        d1 = fmaf(wdq[r+1].x,v.x,d1); d1 = fmaf(wdq[r+1].y,v.y,d1);
        d1 = fmaf(wdq[r+1].z,v.z,d1); d1 = fmaf(wdq[r+1].w,v.w,d1);
        o1 = fmaf(woq[r+1].x,v.x,o1); o1 = fmaf(woq[r+1].y,v.y,o1);
        o1 = fmaf(woq[r+1].z,v.z,o1); o1 = fmaf(woq[r+1].w,v.w,o1);
      }
      float accD = d0+d1, accO = o0+o1;
      accD += __shfl_xor(accD,1); accD += __shfl_xor(accD,2);
      accO += __shfl_xor(accO,1); accO += __shfl_xor(accO,2);
      if (q4==0){
        nxtF[h]   = tanhf(accD + decT[id*H_ + h]);
        logits[h] = accO + b_out[h];
      }
    }
    __syncthreads();

    // ---- P2: scores, register FMA (2 threads/row), nxtF via broadcast reads ----
    { const float4* nf4 = (const float4*)nxtF + half*16;
      float s0=0.f, s1=0.f;
      #pragma unroll
      for (int r=0;r<16;r+=2){
        float4 u = nf4[r], v = nf4[r+1];
        s0 = fmaf(eR4[r].x,u.x,s0);   s0 = fmaf(eR4[r].y,u.y,s0);
        s0 = fmaf(eR4[r].z,u.z,s0);   s0 = fmaf(eR4[r].w,u.w,s0);
        s1 = fmaf(eR4[r+1].x,v.x,s1); s1 = fmaf(eR4[r+1].y,v.y,s1);
        s1 = fmaf(eR4[r+1].z,v.z,s1); s1 = fmaf(eR4[r+1].w,v.w,s1);
      }
      float sacc = s0+s1;
      sacc += __shfl_xor(sacc,1);
      if (half==0) scr[sid] = sacc;
    }
    __syncthreads();

    // ---- P3: wave0 = masked softmax; wave1 = log-softmax of lagged logits -> out row k-1 ----
    if (t < 64){
      float v0 = scr[t];
      float v1 = (t+64  < len)? scr[t+64]  : -1e30f;
      float v2 = (t+128 < len)? scr[t+128] : -1e30f;
      float v3 = (t+192 < len)? scr[t+192] : -1e30f;
      float m = fmaxf(fmaxf(v0,v1), fmaxf(v2,v3));
      #pragma unroll
      for (int o=1;o<64;o<<=1) m = fmaxf(m, __shfl_xor(m,o));
      float e0 = expf(v0-m);
      float e1 = (t+64  < len)? expf(v1-m) : 0.f;
      float e2 = (t+128 < len)? expf(v2-m) : 0.f;
      float e3 = (t+192 < len)? expf(v3-m) : 0.f;
      scr[t]=e0; scr[t+64]=e1; scr[t+128]=e2; scr[t+192]=e3;
      float ss = (e0+e1)+(e2+e3);
      #pragma unroll
      for (int o=1;o<64;o<<=1) ss += __shfl_xor(ss,o);
      if (t==0) red[0] = 1.f/ss;
    } else if (wave == 1 && k >= 2){
      int l = t & 63;
      float a0 = logits[l], a1 = logits[l+64];
      float m = fmaxf(a0,a1);
      #pragma unroll
      for (int o=1;o<64;o<<=1) m = fmaxf(m, __shfl_xor(m,o));
      float ss = expf(a0-m) + expf(a1-m);
      #pragma unroll
      for (int o=1;o<64;o<<=1) ss += __shfl_xor(ss,o);
      float lse = m + logf(ss);
      size_t base = ((size_t)b*S_ + (size_t)(k-1))*(size_t)V_;
      out[base + l]      = a0 - lse;
      out[base + l + 64] = a1 - lse;
    }
    __syncthreads();

    // ---- P4: ctx partials, register FMA (scr broadcasts are 2-way = free) ----
    { float4 ca = make_float4(0.f,0.f,0.f,0.f);
      #pragma unroll
      for (int j=0;j<16;++j){
        float w = scr[g + 16*j];
        ca.x = fmaf(w,cR4[j].x,ca.x); ca.y = fmaf(w,cR4[j].y,ca.y);
        ca.z = fmaf(w,cR4[j].z,ca.z); ca.w = fmaf(w,cR4[j].w,ca.w);
      }
      ctxP4[g*32 + hq] = ca;
    }
    __syncthreads();

    // ---- P5: reduce partials, residual + fold 1/sum ----
    if (t < 32){
      float4 cs = make_float4(0.f,0.f,0.f,0.f);
      #pragma unroll
      for (int g2=0;g2<16;++g2){ float4 p = ctxP4[g2*32 + t];
        cs.x+=p.x; cs.y+=p.y; cs.z+=p.z; cs.w+=p.w; }
      float inv = red[0];
      float4 nx = ((const float4*)nxtF)[t];
      float4 d; d.x = nx.x + cs.x*inv; d.y = nx.y + cs.y*inv;
      d.z = nx.z + cs.z*inv; d.w = nx.w + cs.w*inv;
      ((float4*)decF)[t] = d;
    }
    __syncthreads();
  }

  // -------- epilogue: logits of dec_255 -> out row 255 --------
  { const float4* dp = (const float4*)(decF + q4*32);
    float o0=0.f,o1=0.f;
    #pragma unroll
    for (int r=0;r<8;r+=2){
      float4 u = dp[r^q4], v = dp[(r+1)^q4];
      o0 = fmaf(woq[r].x,u.x,o0);   o0 = fmaf(woq[r].y,u.y,o0);
      o0 = fmaf(woq[r].z,u.z,o0);   o0 = fmaf(woq[r].w,u.w,o0);
      o1 = fmaf(woq[r+1].x,v.x,o1); o1 = fmaf(woq[r+1].y,v.y,o1);
      o1 = fmaf(woq[r+1].z,v.z,o1); o1 = fmaf(woq[r+1].w,v.w,o1);
    }
    float accO = o0+o1;
    accO += __shfl_xor(accO,1); accO += __shfl_xor(accO,2);
    if (q4==0) logits[h] = accO + b_out[h];
  }
  __syncthreads();
  if (t < 64){
    float a0 = logits[t], a1 = logits[t+64];
    float m = fmaxf(a0,a1);
    #pragma unroll
    for (int o=1;o<64;o<<=1) m = fmaxf(m, __shfl_xor(m,o));
    float ss = expf(a0-m) + expf(a1-m);
    #pragma unroll
    for (int o=1;o<64;o<<=1) ss += __shfl_xor(ss,o);
    float lse = m + logf(ss);
    size_t base = ((size_t)b*S_ + (S_-1))*(size_t)V_;
    out[base + t]      = a0 - lse;
    out[base + t + 64] = a1 - lse;
  }
}

extern "C" void kernel_launch(void* const* d_in, const int* in_sizes, int n_in,
                              void* d_out, int out_size, void* d_ws, size_t ws_size,
                              hipStream_t stream)
{
  const void* ohin   = d_in[0];
  const void* ohout  = d_in[1];
  const void* maskp  = d_in[2];
  const void* W_emb  = d_in[3];
  const void* b_emb  = d_in[4];
  const void* W_ih_e = d_in[5];
  const void* W_hh_e = d_in[6];
  const void* b_ih_e = d_in[7];
  const void* b_hh_e = d_in[8];
  const void* W_e2d  = d_in[9];
  const void* b_e2d  = d_in[10];
  const void* W_ih_d = d_in[11];
  const void* W_hh_d = d_in[12];
  const void* b_ih_d = d_in[13];
  const void* b_hh_d = d_in[14];
  const void* W_out  = d_in[15];
  const void* b_out  = d_in[16];
  float* out = (float*)d_out;

  char* ws = (char*)d_ws;
  int* idsIn   = (int*)ws;   ws += (size_t)B_*S_*sizeof(int);
  int* idsOut  = (int*)ws;   ws += (size_t)B_*S_*sizeof(int);
  int* lens    = (int*)ws;   ws += 2048;
  int* flag    = (int*)ws;   ws += 1024;
  float* encT  = (float*)ws; ws += (size_t)V_*H_*sizeof(float);
  float* decT  = (float*)ws; ws += (size_t)V_*H_*sizeof(float);
  float* posT  = (float*)ws; ws += (size_t)V_*H_*sizeof(float);
  float* WheF  = (float*)ws; ws += (size_t)H_*H_*sizeof(float);
  float* WddF  = (float*)ws; ws += (size_t)H_*H_*sizeof(float);
  float* WooF  = (float*)ws; ws += (size_t)H_*H_*sizeof(float);
  float* WedF  = (float*)ws; ws += (size_t)H_*H_*sizeof(float);
  float* be2dF = (float*)ws; ws += 512;
  float* boutF = (float*)ws; ws += 512;

  (void)hipFuncSetAttribute((const void*)k_main,
                            hipFuncAttributeMaxDynamicSharedMemorySize, SMEM_BYTES);

  k_sniff<<<1, 64, 0, stream>>>((const unsigned short*)ohin, flag);
  k_lens<<<2, 256, 0, stream>>>(maskp, lens);
  k_ids<<<(B_*S_)/256, 256, 0, stream>>>(ohin, ohout, flag, idsIn, idsOut);
  k_tables<<<V_, H_, 0, stream>>>(W_emb, b_emb, W_ih_e, b_ih_e, b_hh_e,
                                  W_ih_d, b_ih_d, b_hh_d, flag, encT, decT, posT);
  k_cvt<<<(H_*H_+255)/256, 256, 0, stream>>>(W_hh_e, WheF, H_*H_, flag);
  k_cvt<<<(H_*H_+255)/256, 256, 0, stream>>>(W_hh_d, WddF, H_*H_, flag);
  k_cvt<<<(H_*H_+255)/256, 256, 0, stream>>>(W_out,  WooF, H_*H_, flag);
  k_cvt<<<(H_*H_+255)/256, 256, 0, stream>>>(W_e2d,  WedF, H_*H_, flag);
  k_cvt<<<1, 128, 0, stream>>>(b_e2d, be2dF, H_, flag);
  k_cvt<<<1, 128, 0, stream>>>(b_out, boutF, H_, flag);

  k_main<<<B_, NT_, SMEM_BYTES, stream>>>(idsIn, idsOut, lens, encT, decT, posT,
                                          WheF, WedF, be2dF,
                                          WddF, WooF, boutF, out);
}